// Round 8
// baseline (1335.648 us; speedup 1.0000x reference)
//
#include <hip/hip_runtime.h>

// Problem: mask_logits (256, 1024, 1024) f32 -> out (256,) f32.
// Pass 1 (memory-bound, 1 GiB): per-instance sum(p), sum(p^2), count(x>0),
//   p = sigmoid(x). float4 loads x4-unrolled (4 independent loads in flight
//   per lane), f32 per-thread accum (<=256 elems/thread), double wave/block
//   reduce, double global atomics into d_ws.
// Pass 2 (1 block, 256 threads): mean/std/count -> normalize -> closed-form
//   avg_i = dot(emb_i, s)/N, mean(avg) = dot(s,s)/N^2, out = sigmoid(avg - mean).
// Note: count uses x > 0 (== sigmoid(x) > 0.5 exactly, monotonicity) to avoid
//   threshold flips from fast-exp rounding near p == 0.5.

#define N_INST 256
#define HW_ELEMS (1024 * 1024)
#define BPI 16              // blocks per instance
#define BLOCK 256
#define UNROLL 4

__global__ __launch_bounds__(BLOCK) void atp_reduce_kernel(
    const float* __restrict__ in, double* __restrict__ ws) {
    const int inst = blockIdx.x / BPI;
    const int blk  = blockIdx.x % BPI;

    const float4* __restrict__ p4 =
        reinterpret_cast<const float4*>(in + (size_t)inst * HW_ELEMS);
    const int f4_per_inst = HW_ELEMS / 4;          // 262144
    const int f4_per_blk  = f4_per_inst / BPI;     // 16384
    const int base = blk * f4_per_blk;

    // 4 independent accumulator sets -> 4 loads in flight, short dep chains
    float s[UNROLL]  = {0.f, 0.f, 0.f, 0.f};
    float sq[UNROLL] = {0.f, 0.f, 0.f, 0.f};
    int   c[UNROLL]  = {0, 0, 0, 0};

    // f4_per_blk / (BLOCK*UNROLL) = 16 outer iterations
    for (int i = threadIdx.x; i < f4_per_blk; i += BLOCK * UNROLL) {
        float4 v[UNROLL];
#pragma unroll
        for (int u = 0; u < UNROLL; ++u)
            v[u] = p4[base + i + u * BLOCK];       // independent, coalesced
#pragma unroll
        for (int u = 0; u < UNROLL; ++u) {
            float xs[4] = {v[u].x, v[u].y, v[u].z, v[u].w};
#pragma unroll
            for (int k = 0; k < 4; ++k) {
                float x = xs[k];
                float p = 1.0f / (1.0f + __expf(-x));  // sigmoid
                s[u]  += p;
                sq[u]  = fmaf(p, p, sq[u]);
                c[u]  += (x > 0.0f) ? 1 : 0;           // == (sigmoid(x) > 0.5)
            }
        }
    }

    // merge sets and promote to double for the cross-thread reduction
    double ds = 0.0, dq = 0.0, dc = 0.0;
#pragma unroll
    for (int u = 0; u < UNROLL; ++u) {
        ds += (double)s[u]; dq += (double)sq[u]; dc += (double)c[u];
    }
#pragma unroll
    for (int off = 32; off > 0; off >>= 1) {
        ds += __shfl_down(ds, off);
        dq += __shfl_down(dq, off);
        dc += __shfl_down(dc, off);
    }

    __shared__ double sh[3][BLOCK / 64];
    const int wave = threadIdx.x >> 6;
    const int lane = threadIdx.x & 63;
    if (lane == 0) {
        sh[0][wave] = ds; sh[1][wave] = dq; sh[2][wave] = dc;
    }
    __syncthreads();
    if (threadIdx.x == 0) {
        double ts = 0.0, tq = 0.0, tc = 0.0;
#pragma unroll
        for (int w = 0; w < BLOCK / 64; ++w) {
            ts += sh[0][w]; tq += sh[1][w]; tc += sh[2][w];
        }
        atomicAdd(&ws[inst * 3 + 0], ts);
        atomicAdd(&ws[inst * 3 + 1], tq);
        atomicAdd(&ws[inst * 3 + 2], tc);
    }
}

__global__ __launch_bounds__(N_INST) void atp_finalize_kernel(
    const double* __restrict__ ws, float* __restrict__ out) {
    const int i = threadIdx.x;   // one thread per instance, N_INST == 256

    const double M   = (double)HW_ELEMS;
    double sum   = ws[i * 3 + 0];
    double sumsq = ws[i * 3 + 1];
    double cnt   = ws[i * 3 + 2];

    double mean = sum / M;
    double var  = (sumsq - sum * sum / M) / (M - 1.0);  // ddof=1
    if (var < 0.0) var = 0.0;
    double sd = sqrt(var);

    // F.normalize(dim=1) in f32 like the reference
    float e0 = (float)mean, e1 = (float)sd, e2 = (float)cnt;
    float nrm = sqrtf(e0 * e0 + e1 * e1 + e2 * e2);
    float inv = 1.0f / fmaxf(nrm, 1e-12f);
    e0 *= inv; e1 *= inv; e2 *= inv;

    // s = sum_j emb_j  (3-vector), reduced across the 256 threads
    float s0 = e0, s1 = e1, s2 = e2;
#pragma unroll
    for (int off = 32; off > 0; off >>= 1) {
        s0 += __shfl_down(s0, off);
        s1 += __shfl_down(s1, off);
        s2 += __shfl_down(s2, off);
    }
    __shared__ float sh[3][N_INST / 64];
    const int wave = threadIdx.x >> 6;
    const int lane = threadIdx.x & 63;
    if (lane == 0) { sh[0][wave] = s0; sh[1][wave] = s1; sh[2][wave] = s2; }
    __syncthreads();
    float t0 = 0.0f, t1 = 0.0f, t2 = 0.0f;
#pragma unroll
    for (int w = 0; w < N_INST / 64; ++w) {
        t0 += sh[0][w]; t1 += sh[1][w]; t2 += sh[2][w];
    }

    const float fn = (float)N_INST;
    float avg     = (e0 * t0 + e1 * t1 + e2 * t2) / fn;   // row mean of sim
    float avgmean = (t0 * t0 + t1 * t1 + t2 * t2) / (fn * fn);
    float z = avg - avgmean;
    out[i] = 1.0f / (1.0f + __expf(-z));
}

extern "C" void kernel_launch(void* const* d_in, const int* in_sizes, int n_in,
                              void* d_out, int out_size, void* d_ws, size_t ws_size,
                              hipStream_t stream) {
    const float* in = (const float*)d_in[0];
    float* out = (float*)d_out;
    double* ws = (double*)d_ws;

    // harness poisons d_ws with 0xAA every call — zero the accumulators
    hipMemsetAsync(ws, 0, (size_t)N_INST * 3 * sizeof(double), stream);

    atp_reduce_kernel<<<N_INST * BPI, BLOCK, 0, stream>>>(in, ws);
    atp_finalize_kernel<<<1, N_INST, 0, stream>>>(ws, out);
}